// Round 2
// baseline (1134.525 us; speedup 1.0000x reference)
//
#include <hip/hip_runtime.h>

// VQ-VAE vector quantizer, MI355X (gfx950).
// Round 2: fp64-exact dot, but scoring EMULATES the numpy float32 reference:
//   d_k = fl32( fl32(S_n + B_k) - 2*fl32(dot_nk) ), argmin ties -> smallest k.
// S_n, B_k summation-order errors are row-constant / sub-boundary (harmless);
// exact-rounded dot is within ~4e-9 of any fp32 gemm ordering.
//
// d_out (float32): [0,16777216) quantized; [16777216,16842752) codes; [16842752] vq_loss
// d_ws: [0,8) double loss acc; [64,+4096) float Bf[1024]; [8192,+262144) float Sf[65536]

#define N_PTS   65536
#define K_CODES 1024
#define DIM     256
#define MT      128
#define KT      128
#define DC      64
#define LPAD    65

#define OUT_VALS  16777216
#define OUT_CODES 65536

// one wave per row: fp64 sum of squares, rounded once to fp32
__global__ void sq_rows_kernel(const float* __restrict__ src,
                               float* __restrict__ dst, int nrows) {
  int row  = blockIdx.x * 4 + (threadIdx.x >> 6);
  int lane = threadIdx.x & 63;
  if (row >= nrows) return;
  const float4 v = *(const float4*)(src + (size_t)row * DIM + lane * 4);
  double s = (double)v.x * v.x + (double)v.y * v.y
           + (double)v.z * v.z + (double)v.w * v.w;
#pragma unroll
  for (int off = 32; off > 0; off >>= 1) s += __shfl_down(s, off);
  if (lane == 0) dst[row] = (float)s;
}

// 512 blocks x 256 threads. Block: 128 points x all 1024 codes.
// thread (tx,ty): rows m0+ty+16i (i<8), cols k0+tx+16j (j<8).
__global__ __launch_bounds__(256, 2) void argmin_kernel(
    const float* __restrict__ z, const float* __restrict__ cb,
    const float* __restrict__ Sf, const float* __restrict__ Bf,
    float* __restrict__ codes_out) {
  __shared__ __align__(16) float lds[2 * MT * LPAD];
  float* zt = lds;
  float* ct = lds + MT * LPAD;
  const int t  = threadIdx.x;
  const int tx = t & 15;
  const int ty = t >> 4;
  const int m0 = blockIdx.x * MT;

  float Sf8[8];
#pragma unroll
  for (int i = 0; i < 8; ++i) Sf8[i] = Sf[m0 + ty + 16 * i];

  float bestv[8];
  int   bestk[8];
#pragma unroll
  for (int i = 0; i < 8; ++i) { bestv[i] = 3.0e38f; bestk[i] = 0; }

  for (int k0 = 0; k0 < K_CODES; k0 += KT) {
    double acc[8][8];
#pragma unroll
    for (int i = 0; i < 8; ++i)
#pragma unroll
      for (int j = 0; j < 8; ++j) acc[i][j] = 0.0;

    for (int dc = 0; dc < DIM; dc += DC) {
      __syncthreads();
#pragma unroll
      for (int it = 0; it < 8; ++it) {
        int idx = t + 256 * it;      // 0..2047
        int r   = idx >> 4;          // 0..127
        int f4  = (idx & 15) * 4;    // 0..60
        float4 zv = *(const float4*)(z  + (size_t)(m0 + r) * DIM + dc + f4);
        float4 cv = *(const float4*)(cb + (size_t)(k0 + r) * DIM + dc + f4);
        float* zd = zt + r * LPAD + f4;
        zd[0] = zv.x; zd[1] = zv.y; zd[2] = zv.z; zd[3] = zv.w;
        float* cd = ct + r * LPAD + f4;
        cd[0] = cv.x; cd[1] = cv.y; cd[2] = cv.z; cd[3] = cv.w;
      }
      __syncthreads();
      for (int d = 0; d < DC; ++d) {
        double zr[8], cr[8];
#pragma unroll
        for (int i = 0; i < 8; ++i) zr[i] = (double)zt[(ty + 16 * i) * LPAD + d];
#pragma unroll
        for (int j = 0; j < 8; ++j) cr[j] = (double)ct[(tx + 16 * j) * LPAD + d];
#pragma unroll
        for (int i = 0; i < 8; ++i)
#pragma unroll
          for (int j = 0; j < 8; ++j) acc[i][j] = fma(zr[i], cr[j], acc[i][j]);
      }
    }
    // fp32-emulated scoring: d = fl32( fl32(S+B) - 2*fl32(dot) )
#pragma unroll
    for (int j = 0; j < 8; ++j) {
      int k = k0 + tx + 16 * j;     // ascending k -> strict < keeps first occurrence
      float bk_ = Bf[k];
#pragma unroll
      for (int i = 0; i < 8; ++i) {
        float T1 = Sf8[i] + bk_;
        float v  = T1 - 2.0f * (float)acc[i][j];
        if (v < bestv[i]) { bestv[i] = v; bestk[i] = k; }
      }
    }
  }

  // cross-thread merge over the 16 tx per row; tie -> smaller k (np.argmin first-min)
  __syncthreads();
  float* vals = lds;                    // 128*16 floats = 8192 B
  int*   idxs = (int*)(lds + 2048);     // 128*16 ints   = 8192 B
#pragma unroll
  for (int i = 0; i < 8; ++i) {
    int r = ty + 16 * i;
    vals[r * 16 + tx] = bestv[i];
    idxs[r * 16 + tx] = bestk[i];
  }
  __syncthreads();
  if (t < MT) {
    float bv = vals[t * 16];
    int   bk = idxs[t * 16];
    for (int x = 1; x < 16; ++x) {
      float v  = vals[t * 16 + x];
      int   k2 = idxs[t * 16 + x];
      if (v < bv || (v == bv && k2 < bk)) { bv = v; bk = k2; }
    }
    codes_out[m0 + t] = (float)bk;
  }
}

__global__ void gather_loss_kernel(const float* __restrict__ z,
                                   const float* __restrict__ cb,
                                   float* __restrict__ out,
                                   const float* __restrict__ codes_f,
                                   double* __restrict__ loss) {
  int gid = blockIdx.x * 256 + threadIdx.x;   // 0..4194303
  int n   = gid >> 6;
  int d4  = (gid & 63) * 4;
  int c   = (int)codes_f[n];
  float4 q  = *(const float4*)(cb + (size_t)c * DIM + d4);
  float4 zv = *(const float4*)(z + (size_t)gid * 4);
  *(float4*)(out + (size_t)gid * 4) = q;
  float dx = q.x - zv.x, dy = q.y - zv.y, dz = q.z - zv.z, dw = q.w - zv.w;
  float s = dx * dx + dy * dy + dz * dz + dw * dw;
#pragma unroll
  for (int off = 32; off > 0; off >>= 1) s += __shfl_down(s, off);
  __shared__ float wsum[4];
  int lane = threadIdx.x & 63, wv = threadIdx.x >> 6;
  if (lane == 0) wsum[wv] = s;
  __syncthreads();
  if (threadIdx.x == 0) {
    float tot = wsum[0] + wsum[1] + wsum[2] + wsum[3];
    atomicAdd(loss, (double)tot);
  }
}

__global__ void finalize_kernel(const double* __restrict__ loss,
                                float* __restrict__ out_loss) {
  out_loss[0] = (float)(1.25 * loss[0] / (double)(N_PTS * (size_t)DIM));
}

extern "C" void kernel_launch(void* const* d_in, const int* in_sizes, int n_in,
                              void* d_out, int out_size, void* d_ws, size_t ws_size,
                              hipStream_t stream) {
  const float* z  = (const float*)d_in[0];
  const float* cb = (const float*)d_in[1];
  float* out = (float*)d_out;
  double* ws_loss = (double*)d_ws;
  float* Bf = (float*)((char*)d_ws + 64);
  float* Sf = (float*)((char*)d_ws + 8192);

  hipMemsetAsync(d_ws, 0, 8, stream);
  sq_rows_kernel<<<K_CODES / 4, 256, 0, stream>>>(cb, Bf, K_CODES);
  sq_rows_kernel<<<N_PTS / 4, 256, 0, stream>>>(z, Sf, N_PTS);
  argmin_kernel<<<N_PTS / MT, 256, 0, stream>>>(z, cb, Sf, Bf, out + OUT_VALS);
  gather_loss_kernel<<<(N_PTS * DIM / 4) / 256, 256, 0, stream>>>(
      z, cb, out, out + OUT_VALS, ws_loss);
  finalize_kernel<<<1, 1, 0, stream>>>(ws_loss, out + OUT_VALS + OUT_CODES);
}

// Round 3
// 1115.450 us; speedup vs baseline: 1.0171x; 1.0171x over previous
//
#include <hip/hip_runtime.h>

// VQ-VAE vector quantizer, MI355X (gfx950).
// Round 3: fp32 pass-A argmin with top-2 margin; flagged rows (gap < MARGIN)
// re-resolved by a fp64 fixup kernel that is bit-identical to the round-2
// (verified-passing) emulation: T1=fl32(Sf+Bf), v=fl32(T1-2*fl32(dot64)),
// argmin ties -> smallest k. Flag encoded as code+2048 (cleared by fixup).
//
// d_out (float32): [0,16777216) quantized; [16777216,16842752) codes; [16842752] vq_loss
// d_ws: [0,2048) double loss_slots[256]; [4096,8192) float Bf[1024];
//       [8192,270336) float Sf[65536]   (== round-2 proven footprint)

#define N_PTS    65536
#define K_CODES  1024
#define DIM      256
#define MT       128
#define KT       128
#define DC       32
#define LPAD     33
#define MARGIN   1.0e-4f
#define FLAG_OFF 2048

#define OUT_VALS  16777216
#define OUT_CODES 65536

// one wave per row: fp64 sum of squares, rounded once to fp32
__global__ void sq_rows_kernel(const float* __restrict__ src,
                               float* __restrict__ dst, int nrows) {
  int row  = blockIdx.x * 4 + (threadIdx.x >> 6);
  int lane = threadIdx.x & 63;
  if (row >= nrows) return;
  const float4 v = *(const float4*)(src + (size_t)row * DIM + lane * 4);
  double s = (double)v.x * v.x + (double)v.y * v.y
           + (double)v.z * v.z + (double)v.w * v.w;
#pragma unroll
  for (int off = 32; off > 0; off >>= 1) s += __shfl_down(s, off);
  if (lane == 0) dst[row] = (float)s;
}

// 512 blocks x 256 threads. Block: 128 points x all 1024 codes, fp32.
// thread (tx,ty): rows m0+ty+16i (i<8), cols k0+tx+16j (j<8).
__global__ __launch_bounds__(256, 3) void argmin_f32_kernel(
    const float* __restrict__ z, const float* __restrict__ cb,
    const float* __restrict__ Sf, const float* __restrict__ Bf,
    float* __restrict__ codes_out) {
  __shared__ __align__(16) float lds[2 * MT * LPAD];   // 33792 B
  float* zt = lds;
  float* ct = lds + MT * LPAD;
  const int t  = threadIdx.x;
  const int tx = t & 15;
  const int ty = t >> 4;
  const int m0 = blockIdx.x * MT;

  float Sf8[8];
#pragma unroll
  for (int i = 0; i < 8; ++i) Sf8[i] = Sf[m0 + ty + 16 * i];

  float bestv[8], secv[8];
  int   bestk[8];
#pragma unroll
  for (int i = 0; i < 8; ++i) { bestv[i] = 3.0e38f; secv[i] = 3.0e38f; bestk[i] = 0; }

  for (int k0 = 0; k0 < K_CODES; k0 += KT) {
    float acc[8][8];
#pragma unroll
    for (int i = 0; i < 8; ++i)
#pragma unroll
      for (int j = 0; j < 8; ++j) acc[i][j] = 0.0f;

    for (int dc = 0; dc < DIM; dc += DC) {
      __syncthreads();
      // stage z chunk [128][32] and c chunk [128][32] (pad-33 rows)
#pragma unroll
      for (int it = 0; it < 4; ++it) {
        int idx = t + 256 * it;      // 0..1023
        int r   = idx >> 3;          // 0..127
        int f4  = (idx & 7) * 4;     // 0..28
        float4 zv = *(const float4*)(z  + (size_t)(m0 + r) * DIM + dc + f4);
        float4 cv = *(const float4*)(cb + (size_t)(k0 + r) * DIM + dc + f4);
        float* zd = zt + r * LPAD + f4;
        zd[0] = zv.x; zd[1] = zv.y; zd[2] = zv.z; zd[3] = zv.w;
        float* cd = ct + r * LPAD + f4;
        cd[0] = cv.x; cd[1] = cv.y; cd[2] = cv.z; cd[3] = cv.w;
      }
      __syncthreads();
      for (int d = 0; d < DC; ++d) {
        float zr[8], cr[8];
#pragma unroll
        for (int i = 0; i < 8; ++i) zr[i] = zt[(ty + 16 * i) * LPAD + d];
#pragma unroll
        for (int j = 0; j < 8; ++j) cr[j] = ct[(tx + 16 * j) * LPAD + d];
#pragma unroll
        for (int i = 0; i < 8; ++i)
#pragma unroll
          for (int j = 0; j < 8; ++j) acc[i][j] = fmaf(zr[i], cr[j], acc[i][j]);
      }
    }
    // score + top-2 (k ascending within thread -> strict < keeps first)
#pragma unroll
    for (int j = 0; j < 8; ++j) {
      int k = k0 + tx + 16 * j;
      float bk_ = Bf[k];
#pragma unroll
      for (int i = 0; i < 8; ++i) {
        float T1 = Sf8[i] + bk_;
        float v  = fmaf(-2.0f, acc[i][j], T1);
        bool lt  = v < bestv[i];
        secv[i]  = lt ? bestv[i] : fminf(secv[i], v);
        bestk[i] = lt ? k : bestk[i];
        bestv[i] = lt ? v : bestv[i];
      }
    }
  }

  // cross-thread top-2 merge over the 16 tx per row; tie -> smaller k
  __syncthreads();
  float* vals = lds;                    // 2048 floats
  float* secs = lds + 2048;             // 2048 floats
  int*   idxs = (int*)(lds + 4096);     // 2048 ints
#pragma unroll
  for (int i = 0; i < 8; ++i) {
    int r = ty + 16 * i;
    vals[r * 16 + tx] = bestv[i];
    secs[r * 16 + tx] = secv[i];
    idxs[r * 16 + tx] = bestk[i];
  }
  __syncthreads();
  if (t < MT) {
    float bv = vals[t * 16];
    float sv = secs[t * 16];
    int   bk = idxs[t * 16];
    for (int x = 1; x < 16; ++x) {
      float v1 = vals[t * 16 + x];
      float s1 = secs[t * 16 + x];
      int   k1 = idxs[t * 16 + x];
      bool win = (v1 < bv) || (v1 == bv && k1 < bk);
      sv = win ? fminf(bv, s1) : fminf(sv, v1);
      if (win) { bv = v1; bk = k1; }
    }
    bool flag = (sv - bv) < MARGIN;
    codes_out[m0 + t] = (float)(bk + (flag ? FLAG_OFF : 0));
  }
}

// Re-resolve flagged rows exactly (bit-identical to round-2 emulation).
// 512 blocks x 256 thr; block owns rows [b*128, b*128+128).
__global__ __launch_bounds__(256) void fixup_kernel(
    const float* __restrict__ z, const float* __restrict__ cb,
    const float* __restrict__ Bf, float* __restrict__ codes_out) {
  __shared__ float  zl[DIM];
  __shared__ double sred[256];
  __shared__ float  vred[256];
  __shared__ int    kred[256];
  const int t = threadIdx.x;
  for (int r = 0; r < 128; ++r) {
    int n = blockIdx.x * 128 + r;
    float cf = codes_out[n];              // wave-uniform read
    if (cf < (float)FLAG_OFF) continue;   // uniform branch per block
    zl[t] = z[(size_t)n * DIM + t];
    __syncthreads();
    sred[t] = (double)zl[t] * (double)zl[t];
    __syncthreads();
    for (int off = 128; off > 0; off >>= 1) {
      if (t < off) sred[t] += sred[t + off];
      __syncthreads();
    }
    float Sfl = (float)sred[0];
    float bv = 3.0e38f; int bk = 0;
    for (int j = 0; j < 4; ++j) {
      int k = t * 4 + j;
      const float* crow = cb + (size_t)k * DIM;
      double dot = 0.0;
      for (int d = 0; d < DIM; ++d)
        dot = fma((double)zl[d], (double)crow[d], dot);  // serial d: == round-2 order
      float T1 = Sfl + Bf[k];
      float v  = T1 - 2.0f * (float)dot;
      if (v < bv) { bv = v; bk = k; }     // ascending k -> first occurrence
    }
    vred[t] = bv; kred[t] = bk;
    __syncthreads();
    if (t == 0) {
      for (int x = 1; x < 256; ++x) {
        if (vred[x] < bv || (vred[x] == bv && kred[x] < bk)) { bv = vred[x]; bk = kred[x]; }
      }
      codes_out[n] = (float)bk;           // clears flag
    }
    __syncthreads();
  }
}

__global__ void gather_loss_kernel(const float* __restrict__ z,
                                   const float* __restrict__ cb,
                                   float* __restrict__ out,
                                   const float* __restrict__ codes_f,
                                   double* __restrict__ loss_slots) {
  int gid = blockIdx.x * 256 + threadIdx.x;   // 0..4194303
  int n   = gid >> 6;
  int d4  = (gid & 63) * 4;
  int c   = (int)codes_f[n];
  float4 q  = *(const float4*)(cb + (size_t)c * DIM + d4);
  float4 zv = *(const float4*)(z + (size_t)gid * 4);
  *(float4*)(out + (size_t)gid * 4) = q;
  float dx = q.x - zv.x, dy = q.y - zv.y, dz = q.z - zv.z, dw = q.w - zv.w;
  float s = dx * dx + dy * dy + dz * dz + dw * dw;
#pragma unroll
  for (int off = 32; off > 0; off >>= 1) s += __shfl_down(s, off);
  __shared__ float wsum[4];
  int lane = threadIdx.x & 63, wv = threadIdx.x >> 6;
  if (lane == 0) wsum[wv] = s;
  __syncthreads();
  if (threadIdx.x == 0) {
    float tot = wsum[0] + wsum[1] + wsum[2] + wsum[3];
    atomicAdd(&loss_slots[blockIdx.x & 255], (double)tot);  // 256-way spread
  }
}

__global__ void finalize_kernel(const double* __restrict__ loss_slots,
                                float* __restrict__ out_loss) {
  double s = 0.0;
  for (int i = 0; i < 256; ++i) s += loss_slots[i];
  out_loss[0] = (float)(1.25 * s / (double)(N_PTS * (size_t)DIM));
}

extern "C" void kernel_launch(void* const* d_in, const int* in_sizes, int n_in,
                              void* d_out, int out_size, void* d_ws, size_t ws_size,
                              hipStream_t stream) {
  const float* z  = (const float*)d_in[0];
  const float* cb = (const float*)d_in[1];
  float* out = (float*)d_out;
  double* loss_slots = (double*)d_ws;
  float* Bf = (float*)((char*)d_ws + 4096);
  float* Sf = (float*)((char*)d_ws + 8192);

  hipMemsetAsync(d_ws, 0, 2048, stream);
  sq_rows_kernel<<<K_CODES / 4, 256, 0, stream>>>(cb, Bf, K_CODES);
  sq_rows_kernel<<<N_PTS / 4, 256, 0, stream>>>(z, Sf, N_PTS);
  argmin_f32_kernel<<<N_PTS / MT, 256, 0, stream>>>(z, cb, Sf, Bf, out + OUT_VALS);
  fixup_kernel<<<512, 256, 0, stream>>>(z, cb, Bf, out + OUT_VALS);
  gather_loss_kernel<<<(N_PTS * DIM / 4) / 256, 256, 0, stream>>>(
      z, cb, out, out + OUT_VALS, loss_slots);
  finalize_kernel<<<1, 1, 0, stream>>>(loss_slots, out + OUT_VALS + OUT_CODES);
}

// Round 4
// 819.994 us; speedup vs baseline: 1.3836x; 1.3603x over previous
//
#include <hip/hip_runtime.h>

// VQ-VAE vector quantizer, MI355X (gfx950).
// Round 4: pass-A fp32 argmin WITHOUT the ||z||^2 term (row-constant), top-2
// margin; flagged rows compacted into a ws list; fixup = one block per flagged
// row, exact ref emulation (T1=fl32(S+B), v=fl32(T1-2*fl32(dot64)), first-min
// tie-break). Safety: ref fp32 bucketing reorders only if true gap < 6.2e-5;
// MARGIN=1e-4 with pass-A err ~3e-8.
//
// d_out (float32): [0,16777216) quantized; [16777216,16842752) codes; [16842752] vq_loss
// d_ws: [0,2048) double loss_slots[256]; [2048,2052) int flag_count;
//       [4096,8192) float Bf[1024]; [8192,270336) int flag_list[65536]

#define N_PTS    65536
#define K_CODES  1024
#define DIM      256
#define MT       128
#define KT       128
#define DC       32
#define LPAD     36       // 36*4=144 B row pitch: 16B-aligned rows, 2-way bank alias (free)
#define MARGIN   1.0e-4f

#define OUT_VALS  16777216
#define OUT_CODES 65536

// one wave per row: fp64 sum of squares, rounded once to fp32 (codebook only)
__global__ void sq_rows_kernel(const float* __restrict__ src,
                               float* __restrict__ dst, int nrows) {
  int row  = blockIdx.x * 4 + (threadIdx.x >> 6);
  int lane = threadIdx.x & 63;
  if (row >= nrows) return;
  const float4 v = *(const float4*)(src + (size_t)row * DIM + lane * 4);
  double s = (double)v.x * v.x + (double)v.y * v.y
           + (double)v.z * v.z + (double)v.w * v.w;
#pragma unroll
  for (int off = 32; off > 0; off >>= 1) s += __shfl_down(s, off);
  if (lane == 0) dst[row] = (float)s;
}

// 512 blocks x 256 threads. Block: 128 points x all 1024 codes, fp32.
// thread (tx,ty): rows m0+ty+16i (i<8), cols k0+tx+16j (j<8).
__global__ __launch_bounds__(256, 4) void argmin_f32_kernel(
    const float* __restrict__ z, const float* __restrict__ cb,
    const float* __restrict__ Bf, float* __restrict__ codes_out,
    int* __restrict__ flag_count, int* __restrict__ flag_list) {
  __shared__ __align__(16) float lds[2 * MT * LPAD];   // 36864 B -> 4 blocks/CU
  float* zt = lds;
  float* ct = lds + MT * LPAD;
  const int t  = threadIdx.x;
  const int tx = t & 15;
  const int ty = t >> 4;
  const int m0 = blockIdx.x * MT;

  float bestv[8], secv[8];
  int   bestk[8];
#pragma unroll
  for (int i = 0; i < 8; ++i) { bestv[i] = 3.0e38f; secv[i] = 3.0e38f; bestk[i] = 0; }

  for (int k0 = 0; k0 < K_CODES; k0 += KT) {
    float acc[8][8];
#pragma unroll
    for (int i = 0; i < 8; ++i)
#pragma unroll
      for (int j = 0; j < 8; ++j) acc[i][j] = 0.0f;

    for (int dc = 0; dc < DIM; dc += DC) {
      __syncthreads();
      // stage z chunk [128][32] and c chunk [128][32] (pitch-36, 16B-aligned rows)
#pragma unroll
      for (int it = 0; it < 4; ++it) {
        int idx = t + 256 * it;      // 0..1023
        int r   = idx >> 3;          // 0..127
        int f4  = (idx & 7) * 4;     // 0..28
        float4 zv = *(const float4*)(z  + (size_t)(m0 + r) * DIM + dc + f4);
        float4 cv = *(const float4*)(cb + (size_t)(k0 + r) * DIM + dc + f4);
        *(float4*)(zt + r * LPAD + f4) = zv;   // ds_write_b128
        *(float4*)(ct + r * LPAD + f4) = cv;
      }
      __syncthreads();
      for (int d = 0; d < DC; d += 2) {
        float2 zr2[8], cr2[8];
#pragma unroll
        for (int i = 0; i < 8; ++i)
          zr2[i] = *(const float2*)(zt + (ty + 16 * i) * LPAD + d);  // ds_read_b64
#pragma unroll
        for (int j = 0; j < 8; ++j)
          cr2[j] = *(const float2*)(ct + (tx + 16 * j) * LPAD + d);
#pragma unroll
        for (int i = 0; i < 8; ++i)
#pragma unroll
          for (int j = 0; j < 8; ++j) {
            acc[i][j] = fmaf(zr2[i].x, cr2[j].x, acc[i][j]);
            acc[i][j] = fmaf(zr2[i].y, cr2[j].y, acc[i][j]);
          }
      }
    }
    // score t = B_k - 2*dot (no ||z||^2: row-constant), top-2
#pragma unroll
    for (int j = 0; j < 8; ++j) {
      int k = k0 + tx + 16 * j;      // ascending k -> strict < keeps first
      float bk_ = Bf[k];
#pragma unroll
      for (int i = 0; i < 8; ++i) {
        float v = fmaf(-2.0f, acc[i][j], bk_);
        bool lt  = v < bestv[i];
        secv[i]  = lt ? bestv[i] : fminf(secv[i], v);
        bestk[i] = lt ? k : bestk[i];
        bestv[i] = lt ? v : bestv[i];
      }
    }
  }

  // cross-thread top-2 merge over the 16 tx per row
  __syncthreads();
  float* vals = lds;                    // 2048 floats
  float* secs = lds + 2048;             // 2048 floats
  int*   idxs = (int*)(lds + 4096);     // 2048 ints
#pragma unroll
  for (int i = 0; i < 8; ++i) {
    int r = ty + 16 * i;
    vals[r * 16 + tx] = bestv[i];
    secs[r * 16 + tx] = secv[i];
    idxs[r * 16 + tx] = bestk[i];
  }
  __syncthreads();
  if (t < MT) {
    float bv = vals[t * 16];
    float sv = secs[t * 16];
    int   bk = idxs[t * 16];
    for (int x = 1; x < 16; ++x) {
      float v1 = vals[t * 16 + x];
      float s1 = secs[t * 16 + x];
      int   k1 = idxs[t * 16 + x];
      bool win = (v1 < bv) || (v1 == bv && k1 < bk);
      sv = win ? fminf(bv, s1) : fminf(sv, v1);
      if (win) { bv = v1; bk = k1; }
    }
    codes_out[m0 + t] = (float)bk;
    if (sv - bv < MARGIN) {
      int pos = atomicAdd(flag_count, 1);
      flag_list[pos] = m0 + t;
    }
  }
}

// Exact re-resolution of flagged rows; one block per row (grid-stride).
// Bit-matches the round-2 verified emulation (fp64 dot order-free: exact to 1e-16).
__global__ __launch_bounds__(256) void fixup_kernel(
    const float* __restrict__ z, const float* __restrict__ cb,
    const float* __restrict__ Bf, const int* __restrict__ flag_list,
    const int* __restrict__ flag_count, float* __restrict__ codes_out) {
  __shared__ __align__(16) float zl[DIM];
  __shared__ double sred[256];
  __shared__ float  vred[256];
  __shared__ int    kred[256];
  const int t = threadIdx.x;
  const int cnt = *flag_count;
  for (int i = blockIdx.x; i < cnt; i += gridDim.x) {
    const int n = flag_list[i];
    __syncthreads();                       // protect zl/vred from previous iter
    zl[t] = z[(size_t)n * DIM + t];
    __syncthreads();
    sred[t] = (double)zl[t] * (double)zl[t];
    __syncthreads();
    for (int off = 128; off > 0; off >>= 1) {
      if (t < off) sred[t] += sred[t + off];
      __syncthreads();
    }
    const float Sfl = (float)sred[0];
    float bv = 3.0e38f; int bk = 0;
#pragma unroll
    for (int c = 0; c < 4; ++c) {
      int k = t + 256 * c;                 // ascending k per thread
      const float* crow = cb + (size_t)k * DIM;
      double d0 = 0.0, d1 = 0.0, d2 = 0.0, d3 = 0.0;  // 4 indep chains
      for (int d = 0; d < DIM; d += 4) {
        float4 cv = *(const float4*)(crow + d);
        float4 zv = *(const float4*)(zl + d);
        d0 = fma((double)zv.x, (double)cv.x, d0);
        d1 = fma((double)zv.y, (double)cv.y, d1);
        d2 = fma((double)zv.z, (double)cv.z, d2);
        d3 = fma((double)zv.w, (double)cv.w, d3);
      }
      double dot = (d0 + d1) + (d2 + d3);
      float T1 = Sfl + Bf[k];
      float v  = T1 - 2.0f * (float)dot;
      if (v < bv) { bv = v; bk = k; }
    }
    vred[t] = bv; kred[t] = bk;
    __syncthreads();
    for (int off = 128; off > 0; off >>= 1) {
      if (t < off) {
        float v2 = vred[t + off]; int k2 = kred[t + off];
        if (v2 < vred[t] || (v2 == vred[t] && k2 < kred[t])) {
          vred[t] = v2; kred[t] = k2;
        }
      }
      __syncthreads();
    }
    if (t == 0) codes_out[n] = (float)kred[0];
  }
}

__global__ void gather_loss_kernel(const float* __restrict__ z,
                                   const float* __restrict__ cb,
                                   float* __restrict__ out,
                                   const float* __restrict__ codes_f,
                                   double* __restrict__ loss_slots) {
  int gid = blockIdx.x * 256 + threadIdx.x;   // 0..4194303
  int n   = gid >> 6;
  int d4  = (gid & 63) * 4;
  int c   = (int)codes_f[n];
  float4 q  = *(const float4*)(cb + (size_t)c * DIM + d4);
  float4 zv = *(const float4*)(z + (size_t)gid * 4);
  *(float4*)(out + (size_t)gid * 4) = q;
  float dx = q.x - zv.x, dy = q.y - zv.y, dz = q.z - zv.z, dw = q.w - zv.w;
  float s = dx * dx + dy * dy + dz * dz + dw * dw;
#pragma unroll
  for (int off = 32; off > 0; off >>= 1) s += __shfl_down(s, off);
  __shared__ float wsum[4];
  int lane = threadIdx.x & 63, wv = threadIdx.x >> 6;
  if (lane == 0) wsum[wv] = s;
  __syncthreads();
  if (threadIdx.x == 0) {
    float tot = wsum[0] + wsum[1] + wsum[2] + wsum[3];
    atomicAdd(&loss_slots[blockIdx.x & 255], (double)tot);
  }
}

__global__ void finalize_kernel(const double* __restrict__ loss_slots,
                                float* __restrict__ out_loss) {
  double s = 0.0;
  for (int i = 0; i < 256; ++i) s += loss_slots[i];
  out_loss[0] = (float)(1.25 * s / (double)(N_PTS * (size_t)DIM));
}

extern "C" void kernel_launch(void* const* d_in, const int* in_sizes, int n_in,
                              void* d_out, int out_size, void* d_ws, size_t ws_size,
                              hipStream_t stream) {
  const float* z  = (const float*)d_in[0];
  const float* cb = (const float*)d_in[1];
  float* out = (float*)d_out;
  double* loss_slots = (double*)d_ws;
  int*   flag_count  = (int*)((char*)d_ws + 2048);
  float* Bf          = (float*)((char*)d_ws + 4096);
  int*   flag_list   = (int*)((char*)d_ws + 8192);

  hipMemsetAsync(d_ws, 0, 4096, stream);   // loss slots + flag counter
  sq_rows_kernel<<<K_CODES / 4, 256, 0, stream>>>(cb, Bf, K_CODES);
  argmin_f32_kernel<<<N_PTS / MT, 256, 0, stream>>>(
      z, cb, Bf, out + OUT_VALS, flag_count, flag_list);
  fixup_kernel<<<2048, 256, 0, stream>>>(z, cb, Bf, flag_list, flag_count,
                                         out + OUT_VALS);
  gather_loss_kernel<<<(N_PTS * DIM / 4) / 256, 256, 0, stream>>>(
      z, cb, out, out + OUT_VALS, loss_slots);
  finalize_kernel<<<1, 1, 0, stream>>>(loss_slots, out + OUT_VALS + OUT_CODES);
}

// Round 5
// 768.327 us; speedup vs baseline: 1.4766x; 1.0672x over previous
//
#include <hip/hip_runtime.h>

// VQ-VAE vector quantizer, MI355X (gfx950).
// Round 5: pass-A via bf16 MFMA (16x16x32). z split hi+lo bf16 (2 passes vs
// codebook-hi): dot err ~1e-5 << MARGIN. Top-2 margin; flagged rows -> exact
// fp64 fixup (bit-matches round-2 verified ref emulation).
//
// d_out (float32): [0,16777216) quantized; [16777216,16842752) codes; [16842752] vq_loss
//   (bytes [0, 524288) of d_out double as cbh_perm scratch until gather overwrites)
// d_ws: [0,2048) double loss_slots[256]; [2048,2052) int flag_count;
//       [4096,8192) float Bf[1024]; [8192,270336) int flag_list[65536]

#define N_PTS    65536
#define K_CODES  1024
#define DIM      256
#define MARGIN   4.0e-4f

#define OUT_VALS  16777216
#define OUT_CODES 65536

typedef __attribute__((ext_vector_type(8))) short short8v;
typedef __attribute__((ext_vector_type(4))) float float4v;

__device__ __forceinline__ short f2bf(float x) {
  union { float f; unsigned u; } v; v.f = x;
  unsigned r = v.u + 0x7fff + ((v.u >> 16) & 1);   // RTN-even
  return (short)(r >> 16);
}
__device__ __forceinline__ float bf2f(short h) {
  union { unsigned u; float f; } v; v.u = ((unsigned)(unsigned short)h) << 16;
  return v.f;
}

// perm index (in shorts) for codebook element (r, k):
// chunk = ((r>>4)*8 + (k>>5))*4 + ((k>>3)&3); idx = chunk*128 + (r&15)*8 + (k&7)
__device__ __forceinline__ int perm_idx(int r, int k) {
  return ((((r >> 4) * 8 + (k >> 5)) * 4 + ((k >> 3) & 3)) * 128) + (r & 15) * 8 + (k & 7);
}

// one wave per code row: Bf[r] = fl32(fp64 sum of squares); also emit bf16-hi
// codebook in B-fragment-permuted order. grid 256 x 256.
__global__ void prep_cb_kernel(const float* __restrict__ cb,
                               short* __restrict__ cbh_perm,
                               float* __restrict__ Bf) {
  int r    = blockIdx.x * 4 + (threadIdx.x >> 6);
  int lane = threadIdx.x & 63;
  const float4 v = *(const float4*)(cb + (size_t)r * DIM + lane * 4);
  double s = (double)v.x * v.x + (double)v.y * v.y
           + (double)v.z * v.z + (double)v.w * v.w;
#pragma unroll
  for (int off = 32; off > 0; off >>= 1) s += __shfl_down(s, off);
  if (lane == 0) Bf[r] = (float)s;
  short4 h = make_short4(f2bf(v.x), f2bf(v.y), f2bf(v.z), f2bf(v.w));
  *(short4*)(cbh_perm + perm_idx(r, lane * 4)) = h;   // (k&7)∈{0,4}: 8B aligned
}

// 1024 blocks x 256 thr (4 waves). Block: 64 points x all 1024 codes.
// Wave w: 16 points. A-frags resident (hi+lo). Codes iterated 32 at a time.
__global__ __launch_bounds__(256, 4) void argmin_mfma_kernel(
    const float* __restrict__ z, const short* __restrict__ cbh_perm,
    const float* __restrict__ Bf, float* __restrict__ codes_out,
    int* __restrict__ flag_count, int* __restrict__ flag_list) {
  __shared__ __align__(16) short lbuf[8192];   // 16 KB: 32 codes x 256 d, frag order
  const int t    = threadIdx.x;
  const int w    = t >> 6;
  const int l    = t & 63;
  const int quad = l >> 4;
  const int lr   = l & 15;
  const int m0   = blockIdx.x * 64;

  // A-fragments: lane holds A[m=lr][k=q*32+quad*8+j], split bf16 hi/lo
  short8v ah[8], al[8];
  {
    const float* zrow = z + (size_t)(m0 + w * 16 + lr) * DIM;
#pragma unroll
    for (int q = 0; q < 8; ++q) {
      float4 p0 = *(const float4*)(zrow + q * 32 + quad * 8);
      float4 p1 = *(const float4*)(zrow + q * 32 + quad * 8 + 4);
      float e[8] = {p0.x, p0.y, p0.z, p0.w, p1.x, p1.y, p1.z, p1.w};
      short8v h, lo;
#pragma unroll
      for (int j = 0; j < 8; ++j) {
        short hb = f2bf(e[j]);
        h[j]  = hb;
        lo[j] = f2bf(e[j] - bf2f(hb));
      }
      ah[q] = h; al[q] = lo;
    }
  }

  float bestv[4], secv[4]; int bestk[4];
#pragma unroll
  for (int r = 0; r < 4; ++r) { bestv[r] = 3.0e38f; secv[r] = 3.0e38f; bestk[r] = 0; }

  for (int c0 = 0; c0 < K_CODES; c0 += 32) {
    __syncthreads();
    // stage 16KB contiguous (perm layout == LDS layout)
    const short* src = cbh_perm + c0 * 256;
#pragma unroll
    for (int i = 0; i < 4; ++i)
      *(float4*)(lbuf + t * 8 + i * 2048) = *(const float4*)(src + t * 8 + i * 2048);
    __syncthreads();

#pragma unroll
    for (int st = 0; st < 2; ++st) {
      float4v acc = {0.f, 0.f, 0.f, 0.f};
#pragma unroll
      for (int q = 0; q < 8; ++q) {
        // B-frag: lane holds B[k=quad*8+j][n=lr] == cb[n][k] (B^T rows)
        short8v b = *(const short8v*)(lbuf + (st * 8 + q) * 512 + quad * 128 + lr * 8);
        acc = __builtin_amdgcn_mfma_f32_16x16x32_bf16(al[q], b, acc, 0, 0, 0);
        acc = __builtin_amdgcn_mfma_f32_16x16x32_bf16(ah[q], b, acc, 0, 0, 0);
      }
      const int k = c0 + st * 16 + lr;       // this lane's code (C col = lane&15)
      const float bk_ = Bf[k];
#pragma unroll
      for (int r = 0; r < 4; ++r) {          // C row = quad*4 + r (point)
        float v = fmaf(-2.0f, acc[r], bk_);
        bool lt  = v < bestv[r];
        secv[r]  = lt ? bestv[r] : fminf(secv[r], v);
        bestk[r] = lt ? k : bestk[r];
        bestv[r] = lt ? v : bestv[r];
      }
    }
  }

  // top-2 merge across the 16 col-lanes of each quad (butterfly)
#pragma unroll
  for (int mask = 1; mask < 16; mask <<= 1) {
#pragma unroll
    for (int r = 0; r < 4; ++r) {
      float ov = __shfl_xor(bestv[r], mask);
      float os = __shfl_xor(secv[r], mask);
      int   ok = __shfl_xor(bestk[r], mask);
      bool win = (ov < bestv[r]) || (ov == bestv[r] && ok < bestk[r]);
      float ns = win ? fminf(bestv[r], os) : fminf(secv[r], ov);
      bestv[r] = win ? ov : bestv[r];
      bestk[r] = win ? ok : bestk[r];
      secv[r]  = ns;
    }
  }
  if (lr == 0) {
#pragma unroll
    for (int r = 0; r < 4; ++r) {
      int n = m0 + w * 16 + quad * 4 + r;
      codes_out[n] = (float)bestk[r];
      if (secv[r] - bestv[r] < MARGIN) {
        int pos = atomicAdd(flag_count, 1);
        flag_list[pos] = n;
      }
    }
  }
}

// Exact re-resolution of flagged rows; one block per row (grid-stride).
// Bit-matches round-2 verified emulation: v = fl32(fl32(S+B) - 2*fl32(dot64)).
__global__ __launch_bounds__(256) void fixup_kernel(
    const float* __restrict__ z, const float* __restrict__ cb,
    const float* __restrict__ Bf, const int* __restrict__ flag_list,
    const int* __restrict__ flag_count, float* __restrict__ codes_out) {
  __shared__ __align__(16) float zl[DIM];
  __shared__ double sred[256];
  __shared__ float  vred[256];
  __shared__ int    kred[256];
  const int t = threadIdx.x;
  const int cnt = *flag_count;
  for (int i = blockIdx.x; i < cnt; i += gridDim.x) {
    const int n = flag_list[i];
    __syncthreads();
    zl[t] = z[(size_t)n * DIM + t];
    __syncthreads();
    sred[t] = (double)zl[t] * (double)zl[t];
    __syncthreads();
    for (int off = 128; off > 0; off >>= 1) {
      if (t < off) sred[t] += sred[t + off];
      __syncthreads();
    }
    const float Sfl = (float)sred[0];
    float bv = 3.0e38f; int bk = 0;
#pragma unroll
    for (int c = 0; c < 4; ++c) {
      int k = t + 256 * c;
      const float* crow = cb + (size_t)k * DIM;
      double d0 = 0.0, d1 = 0.0, d2 = 0.0, d3 = 0.0;
      for (int d = 0; d < DIM; d += 4) {
        float4 cv = *(const float4*)(crow + d);
        float4 zv = *(const float4*)(zl + d);
        d0 = fma((double)zv.x, (double)cv.x, d0);
        d1 = fma((double)zv.y, (double)cv.y, d1);
        d2 = fma((double)zv.z, (double)cv.z, d2);
        d3 = fma((double)zv.w, (double)cv.w, d3);
      }
      double dot = (d0 + d1) + (d2 + d3);
      float T1 = Sfl + Bf[k];
      float v  = T1 - 2.0f * (float)dot;
      if (v < bv) { bv = v; bk = k; }
    }
    vred[t] = bv; kred[t] = bk;
    __syncthreads();
    for (int off = 128; off > 0; off >>= 1) {
      if (t < off) {
        float v2 = vred[t + off]; int k2 = kred[t + off];
        if (v2 < vred[t] || (v2 == vred[t] && k2 < kred[t])) {
          vred[t] = v2; kred[t] = k2;
        }
      }
      __syncthreads();
    }
    if (t == 0) codes_out[n] = (float)kred[0];
  }
}

__global__ void gather_loss_kernel(const float* __restrict__ z,
                                   const float* __restrict__ cb,
                                   float* __restrict__ out,
                                   const float* __restrict__ codes_f,
                                   double* __restrict__ loss_slots) {
  int gid = blockIdx.x * 256 + threadIdx.x;
  int n   = gid >> 6;
  int d4  = (gid & 63) * 4;
  int c   = (int)codes_f[n];
  float4 q  = *(const float4*)(cb + (size_t)c * DIM + d4);
  float4 zv = *(const float4*)(z + (size_t)gid * 4);
  *(float4*)(out + (size_t)gid * 4) = q;
  float dx = q.x - zv.x, dy = q.y - zv.y, dz = q.z - zv.z, dw = q.w - zv.w;
  float s = dx * dx + dy * dy + dz * dz + dw * dw;
#pragma unroll
  for (int off = 32; off > 0; off >>= 1) s += __shfl_down(s, off);
  __shared__ float wsum[4];
  int lane = threadIdx.x & 63, wv = threadIdx.x >> 6;
  if (lane == 0) wsum[wv] = s;
  __syncthreads();
  if (threadIdx.x == 0) {
    float tot = wsum[0] + wsum[1] + wsum[2] + wsum[3];
    atomicAdd(&loss_slots[blockIdx.x & 255], (double)tot);
  }
}

__global__ void finalize_kernel(const double* __restrict__ loss_slots,
                                float* __restrict__ out_loss) {
  double s = 0.0;
  for (int i = 0; i < 256; ++i) s += loss_slots[i];
  out_loss[0] = (float)(1.25 * s / (double)(N_PTS * (size_t)DIM));
}

extern "C" void kernel_launch(void* const* d_in, const int* in_sizes, int n_in,
                              void* d_out, int out_size, void* d_ws, size_t ws_size,
                              hipStream_t stream) {
  const float* z  = (const float*)d_in[0];
  const float* cb = (const float*)d_in[1];
  float* out = (float*)d_out;
  double* loss_slots = (double*)d_ws;
  int*   flag_count  = (int*)((char*)d_ws + 2048);
  float* Bf          = (float*)((char*)d_ws + 4096);
  int*   flag_list   = (int*)((char*)d_ws + 8192);
  short* cbh_perm    = (short*)d_out;   // scratch in out[0:131072); gather overwrites later

  hipMemsetAsync(d_ws, 0, 4096, stream);
  prep_cb_kernel<<<K_CODES / 4, 256, 0, stream>>>(cb, cbh_perm, Bf);
  argmin_mfma_kernel<<<N_PTS / 64, 256, 0, stream>>>(
      z, cbh_perm, Bf, out + OUT_VALS, flag_count, flag_list);
  fixup_kernel<<<2048, 256, 0, stream>>>(z, cb, Bf, flag_list, flag_count,
                                         out + OUT_VALS);
  gather_loss_kernel<<<(N_PTS * DIM / 4) / 256, 256, 0, stream>>>(
      z, cb, out, out + OUT_VALS, loss_slots);
  finalize_kernel<<<1, 1, 0, stream>>>(loss_slots, out + OUT_VALS + OUT_CODES);
}